// Round 7
// baseline (43.084 us; speedup 1.0000x reference)
//
#include <hip/hip_runtime.h>
#include <hip/hip_bf16.h>

typedef __attribute__((ext_vector_type(8))) short short8;
typedef __attribute__((ext_vector_type(4))) float floatx4;
typedef __attribute__((ext_vector_type(2))) float floatx2;

#define B_ROWS 8192
#define DIM    128
#define NSPLIT 16
#define JSPAN  (B_ROWS / NSPLIT)        // 512 cols per split
#define NTILE  (JSPAN / 16)             // 32 j-tiles of 16 cols
#define WAVES  4
#define RPW    64                       // rows per wave (4 x 16-row MFMA sets)
#define BM     (WAVES * RPW)            // 256 rows per block
#define NRB    (B_ROWS / BM)            // 32 row-blocks -> 512 blocks = 2/CU
#define BIAS   4096.0f

// Fragment-ordered buffer xf: for 16-row tile t, k-slice kk (0..3), lane l (0..63):
//   bf16 index = t*2048 + kk*512 + l*8 + e
// = element (row = t*16 + (l&15), k = kk*32 + (l>>4)*8 + e), i.e. the exact
// mfma_f32_16x16x32_bf16 A/B fragment layout. One tile = 4KB contiguous.

// ws layout
#define OFF_SQ    (2u << 20)
#define OFF_SQLAB (OFF_SQ + (64u << 10))     // float2 {sq, lab_bits} per col, 64KB
#define OFF_D2P   (OFF_SQLAB + (64u << 10))
#define OFF_D2N   (OFF_D2P + (512u << 10))
#define OFF_ACC   (OFF_D2N + (512u << 10))   // float sum, int done

// global -> LDS direct copy, 16B per lane; LDS dest = wave-uniform base + lane*16
#define GLOAD_LDS(g, l) __builtin_amdgcn_global_load_lds(                     \
    (const __attribute__((address_space(1))) void*)(g),                       \
    (__attribute__((address_space(3))) void*)(l), 16, 0, 0)

// ---------------- prep: f32 -> bf16 fragment-order + norms + packed sq/lab ----------------
__global__ __launch_bounds__(256) void prep_kernel(const float* __restrict__ x,
                                                   const int* __restrict__ lab,
                                                   __hip_bfloat16* __restrict__ xf,
                                                   float* __restrict__ sq,
                                                   float2* __restrict__ sqlab,
                                                   float* __restrict__ acc_sum,
                                                   int* __restrict__ done) {
    if (blockIdx.x == 0 && threadIdx.x == 0) { acc_sum[0] = 0.f; done[0] = 0; }
    const int row  = blockIdx.x * 4 + (threadIdx.x >> 6);
    const int lane = threadIdx.x & 63;   // holds k = 2*lane, 2*lane+1
    const float2 v = *reinterpret_cast<const float2*>(x + row * DIM + lane * 2);
    __hip_bfloat162 b2;
    b2.x = __float2bfloat16(v.x);
    b2.y = __float2bfloat16(v.y);
    // fragment-order address for k0 = 2*lane
    const int kk = lane >> 4;
    const int g  = (lane >> 2) & 3;
    const int e  = (lane & 3) * 2;
    const int idx = (row >> 4) * 2048 + kk * 512 + (g * 16 + (row & 15)) * 8 + e;
    *reinterpret_cast<__hip_bfloat162*>(xf + idx) = b2;
    float s = v.x * v.x + v.y * v.y;
    #pragma unroll
    for (int m = 1; m < 64; m <<= 1) s += __shfl_xor(s, m, 64);
    if (lane == 0) {
        sq[row] = s;
        float2 p; p.x = s; p.y = __int_as_float(lab[row]);
        sqlab[row] = p;
    }
}

// ---------------- main: LDS-staged Gram + biased hardest pos/neg ----------------
// grid = (NRB, NSPLIT), block = 256 (4 waves). B tiles staged to LDS ONCE per
// block via global_load_lds (16B/lane), 4-deep ring, counted vmcnt(2), one raw
// s_barrier per tile. Wave owns 64 rows; A fragments + running max/min in regs.
// t = sq_j - 2*dot + BIAS*same.  max t = hardest_pos + BIAS; min t = hardest_neg.
__global__ __launch_bounds__(256, 2) void main_kernel(
    const __hip_bfloat16* __restrict__ xf,
    const float* __restrict__ sq,
    const int*  __restrict__ lab,
    const float2* __restrict__ sqlab,
    float* __restrict__ d2p,   // [NSPLIT][B_ROWS]
    float* __restrict__ d2n) { // [NSPLIT][B_ROWS]
    __shared__ __align__(16) char ldsT[4][4096];   // 4-deep tile ring (4KB tiles)
    __shared__ __align__(16) char ldsS[4096];      // split's 512 x {sq, lab} pairs

    const int tid  = threadIdx.x;
    const int lane = tid & 63;
    const int wave = tid >> 6;
    const int l15  = lane & 15;
    const int g    = lane >> 4;
    const int rowbase = blockIdx.x * BM + wave * RPW;
    const int split   = blockIdx.y;
    const int jstart  = split * JSPAN;

    // ---- prologue: stage sqlab + tiles 0,1,2 (4 outstanding gload_lds) ----
    {
        const char* gs = (const char*)sqlab + (size_t)jstart * 8;
        GLOAD_LDS(gs + tid * 16, &ldsS[wave * 1024]);
        const char* gt = (const char*)xf + (size_t)(jstart >> 4) * 4096;
        GLOAD_LDS(gt +      tid * 16, &ldsT[0][wave * 1024]);
        GLOAD_LDS(gt + 4096 + tid * 16, &ldsT[1][wave * 1024]);
        GLOAD_LDS(gt + 8192 + tid * 16, &ldsT[2][wave * 1024]);
    }

    // A fragments: 4 sets x 16 rows, contiguous loads from xf
    short8 a[4][4];
    #pragma unroll
    for (int s = 0; s < 4; ++s) {
        const __hip_bfloat16* ap = xf + ((size_t)(rowbase >> 4) + s) * 2048 + lane * 8;
        #pragma unroll
        for (int kk = 0; kk < 4; ++kk)
            a[s][kk] = *reinterpret_cast<const short8*>(ap + kk * 512);
    }
    // Labels of owned rows per C/D reg (row = s*16 + g*4 + q)
    int labi[4][4];
    #pragma unroll
    for (int s = 0; s < 4; ++s)
        #pragma unroll
        for (int q = 0; q < 4; ++q)
            labi[s][q] = lab[rowbase + s * 16 + g * 4 + q];

    float mx[4][4], mn[4][4];
    #pragma unroll
    for (int s = 0; s < 4; ++s)
        #pragma unroll
        for (int q = 0; q < 4; ++q) { mx[s][q] = -INFINITY; mn[s][q] = INFINITY; }

    #define STAGE(buf_, tile_) GLOAD_LDS(                                     \
        (const char*)xf + ((size_t)(jstart >> 4) + (unsigned)(tile_)) * 4096  \
            + tid * 16,                                                       \
        &ldsT[buf_][wave * 1024])

    for (int jt = 0; jt < NTILE; ++jt) {
        // my slice of tile jt has landed (2 newest stages may remain in flight)
        asm volatile("s_waitcnt vmcnt(2)" ::: "memory");
        __builtin_amdgcn_s_barrier();   // all 4 waves' slices of tile jt landed
        // stage tile jt+3 into the ring slot freed at the previous barrier
        STAGE((jt + 3) & 3, (jt + 3) & 31);

        const int buf = jt & 3;
        short8 b[4];
        #pragma unroll
        for (int kk = 0; kk < 4; ++kk)
            b[kk] = *reinterpret_cast<const short8*>(&ldsT[buf][kk * 1024 + lane * 16]);
        const floatx2 sl = *reinterpret_cast<const floatx2*>(&ldsS[(jt * 16 + l15) * 8]);
        const float sqj  = sl[0];
        const int   labj = __float_as_int(sl[1]);

        floatx4 acc[4];
        #pragma unroll
        for (int s = 0; s < 4; ++s) acc[s] = (floatx4){0.f, 0.f, 0.f, 0.f};
        #pragma unroll
        for (int kk = 0; kk < 4; ++kk) {
            #pragma unroll
            for (int s = 0; s < 4; ++s)
                acc[s] = __builtin_amdgcn_mfma_f32_16x16x32_bf16(a[s][kk], b[kk], acc[s], 0, 0, 0);
        }

        const float sqjb = sqj + BIAS;
        #pragma unroll
        for (int s = 0; s < 4; ++s) {
            #pragma unroll
            for (int q = 0; q < 4; ++q) {
                const float t = fmaf(-2.f, acc[s][q], (labj == labi[s][q]) ? sqjb : sqj);
                mx[s][q] = fmaxf(mx[s][q], t);
                mn[s][q] = fminf(mn[s][q], t);
            }
        }
    }
    #undef STAGE

    // reduce over the 16 cols held by the 16 lanes of each g-group
    #pragma unroll
    for (int s = 0; s < 4; ++s)
        #pragma unroll
        for (int q = 0; q < 4; ++q) {
            #pragma unroll
            for (int mk = 1; mk < 16; mk <<= 1) {
                mx[s][q] = fmaxf(mx[s][q], __shfl_xor(mx[s][q], mk, 64));
                mn[s][q] = fminf(mn[s][q], __shfl_xor(mn[s][q], mk, 64));
            }
        }
    if (l15 == 0) {
        #pragma unroll
        for (int s = 0; s < 4; ++s)
            #pragma unroll
            for (int q = 0; q < 4; ++q) {
                const int i = rowbase + s * 16 + g * 4 + q;
                const float sqi = sq[i];
                d2p[split * B_ROWS + i] = sqi + (mx[s][q] - BIAS);
                d2n[split * B_ROWS + i] = sqi + mn[s][q];
            }
    }
}

// ---------------- combine: splits -> per-row loss -> scalar ----------------
__global__ __launch_bounds__(256) void combine_kernel(
    const float* __restrict__ d2p, const float* __restrict__ d2n,
    float* __restrict__ acc_sum, int* __restrict__ done,
    float* __restrict__ out) {
    const int row = blockIdx.x * 256 + threadIdx.x;
    float p = -INFINITY, n = INFINITY;
    #pragma unroll
    for (int s = 0; s < NSPLIT; ++s) {
        p = fmaxf(p, d2p[s * B_ROWS + row]);
        n = fminf(n, d2n[s * B_ROWS + row]);
    }
    float v = fmaxf(sqrtf(fmaxf(p, 0.f)) - sqrtf(fmaxf(n, 0.f)) + 1.0f, 0.f);
    #pragma unroll
    for (int mk = 1; mk < 64; mk <<= 1) v += __shfl_xor(v, mk, 64);
    __shared__ float sv[4];
    const int wv = threadIdx.x >> 6;
    if ((threadIdx.x & 63) == 0) sv[wv] = v;
    __syncthreads();
    if (threadIdx.x == 0) {
        atomicAdd(acc_sum, sv[0] + sv[1] + sv[2] + sv[3]);
        __threadfence();
        const int old = atomicAdd(done, 1);
        if (old == (int)gridDim.x - 1) {
            const float fs = atomicAdd(acc_sum, 0.f);   // coherent read
            out[0] = fs / (float)B_ROWS;
        }
    }
}

// ---------------- launch ----------------
extern "C" void kernel_launch(void* const* d_in, const int* in_sizes, int n_in,
                              void* d_out, int out_size, void* d_ws, size_t ws_size,
                              hipStream_t stream) {
    const float* x   = (const float*)d_in[0];
    const int*   lab = (const int*)d_in[1];
    float*       out = (float*)d_out;

    char* ws = (char*)d_ws;
    __hip_bfloat16* xf = (__hip_bfloat16*)ws;
    float*  sq      = (float*)(ws + OFF_SQ);
    float2* sqlab   = (float2*)(ws + OFF_SQLAB);
    float*  d2p     = (float*)(ws + OFF_D2P);
    float*  d2n     = (float*)(ws + OFF_D2N);
    float*  acc_sum = (float*)(ws + OFF_ACC);
    int*    done    = (int*)(ws + OFF_ACC + 4);

    prep_kernel<<<B_ROWS / 4, 256, 0, stream>>>(x, lab, xf, sq, sqlab, acc_sum, done);
    main_kernel<<<dim3(NRB, NSPLIT), 256, 0, stream>>>(xf, sq, lab, sqlab, d2p, d2n);
    combine_kernel<<<B_ROWS / 256, 256, 0, stream>>>(d2p, d2n, acc_sum, done, out);
}